// Round 3
// baseline (332.621 us; speedup 1.0000x reference)
//
#include <hip/hip_runtime.h>

// CRF negative mean log-likelihood, B=64, T=512, U=256.
//
// Round 2 (resubmit; round-2 bench hit GPU-acquisition timeout):
// 4 waves/WG (was 8). Per-wave A-fragment LDS reads are constant
// (8 ds_read_b128/step) regardless of n-tile count, so 4 fat waves halve the
// LDS pipe traffic per step (the round-1 bottleneck: 64 b128/step/CU).
// 1 wave/SIMD -> no issue-port sharing; 4-wave barrier is cheaper.
// Final mean fused via last-block atomic (counter base = 0xAA poison).

#define Bc 64
#define Tc 512
#define Uc 256
#define LOG2E 1.4426950408889634f
#define LN2   0.6931471805599453f

typedef __bf16 bf16x8 __attribute__((ext_vector_type(8)));
typedef float  f32x4  __attribute__((ext_vector_type(4)));

__device__ __forceinline__ float wave_max64(float v) {
    v = fmaxf(v, __shfl_xor(v, 1));
    v = fmaxf(v, __shfl_xor(v, 2));
    v = fmaxf(v, __shfl_xor(v, 4));
    v = fmaxf(v, __shfl_xor(v, 8));
    v = fmaxf(v, __shfl_xor(v, 16));
    v = fmaxf(v, __shfl_xor(v, 32));
    return v;
}
__device__ __forceinline__ float wave_sum64(float v) {
    v += __shfl_xor(v, 1);
    v += __shfl_xor(v, 2);
    v += __shfl_xor(v, 4);
    v += __shfl_xor(v, 8);
    v += __shfl_xor(v, 16);
    v += __shfl_xor(v, 32);
    return v;
}

// Raw barrier: does NOT drain vmcnt (keeps pot prefetch loads in flight).
// lgkmcnt(0) makes our ds_write visible first; asm memory clobbers stop LLVM
// from moving LDS accesses across it.
__device__ __forceinline__ void wg_barrier() {
    asm volatile("s_waitcnt lgkmcnt(0)" ::: "memory");
    __builtin_amdgcn_s_barrier();
    asm volatile("" ::: "memory");
}

__global__ __launch_bounds__(256, 1)
void crf_fwd(const float* __restrict__ pot, const int* __restrict__ tags,
             const int* __restrict__ seqlen, const float* __restrict__ trans,
             float* __restrict__ ws, float* __restrict__ out)
{
    const int b    = blockIdx.x;
    const int tid  = threadIdx.x;          // 0..255 ; u_mine == tid
    const int lane = tid & 63;
    const int w    = tid >> 6;             // wave 0..3
    const int g4   = lane >> 4;            // k-group 0..3
    const int c16  = lane & 15;            // fragment column
    const int L    = seqlen[b];

    __shared__ __align__(16) __bf16 ea_lds[2][Uc];
    __shared__ float wred[4];
    __shared__ float redU[4], redB[4];

    const float* potb = pot  + (size_t)b * Tc * Uc;
    const int*   tagb = tags + b * Tc;

    // ---- B fragments: E = exp(trans), bf16, resident in registers ----
    // wave w owns n-tiles nt=0..3 (u in [64w, 64w+64)).
    // elem e of lane l = E[v = 32*kt + 8*g4 + e][u = 64w + 16nt + c16].
    // Same (lane,e)->k placement as the A fragments, so any HW k-permutation
    // cancels (verified absmax 0.0 in round 1).
    bf16x8 bfr[8][4];
    #pragma unroll
    for (int kt = 0; kt < 8; ++kt) {
        #pragma unroll
        for (int nt = 0; nt < 4; ++nt) {
            const int u = 64 * w + 16 * nt + c16;
            bf16x8 bb;
            #pragma unroll
            for (int e = 0; e < 8; ++e) {
                const int v = 32 * kt + 8 * g4 + e;
                bb[e] = (__bf16)__builtin_exp2f(trans[v * Uc + u] * LOG2E);
            }
            bfr[kt][nt] = bb;
        }
    }

    // ---- prologue: unary + binary scores, block-parallel over t ----
    {
        float up = 0.f, bp = 0.f;
        #pragma unroll
        for (int tt0 = 0; tt0 < Tc; tt0 += 256) {
            const int t = tt0 + tid;
            const int tg = tagb[t];
            if (t < L)           up += potb[(size_t)t * Uc + tg];
            if (t >= 1 && t < L) bp += trans[tagb[t - 1] * Uc + tg];
        }
        up = wave_sum64(up);
        bp = wave_sum64(bp);
        if (lane == 0) { redU[w] = up; redB[w] = bp; }
    }
    __syncthreads();

    // pot prefetch registers, t = 1..4 (u_mine == tid)
    float pv0 = potb[(size_t)1 * Uc + tid];
    float pv1 = potb[(size_t)2 * Uc + tid];
    float pv2 = potb[(size_t)3 * Uc + tid];
    float pv3 = potb[(size_t)4 * Uc + tid];

    // ---- init (t = 0): ea = exp(pot0) / g, M = log g ----
    float er = __builtin_exp2f(potb[tid] * LOG2E);
    float M;
    {
        float m = wave_max64(er);
        if (lane == 0) wred[w] = m;
        __syncthreads();
        float g = fmaxf(fmaxf(wred[0], wred[1]), fmaxf(wred[2], wred[3]));
        M  = LN2 * __builtin_log2f(g);
        er = er * __builtin_amdgcn_rcpf(g);
        ea_lds[0][tid] = (__bf16)er;
        __syncthreads();
    }

    // One recursion step. Reads ea from ea_lds[RP], writes ea' to ea_lds[WP].
    // 8 A-fragment reads feed 32 MFMAs as 8 independent depth-4 chains.
    #define STEPBODY(TT, PVC, RP, WP)                                          \
    {                                                                          \
        bf16x8 af[8];                                                          \
        const __bf16* ebase = &ea_lds[(RP)][8 * g4];                           \
        _Pragma("unroll")                                                      \
        for (int kt = 0; kt < 8; ++kt)                                         \
            af[kt] = *(const bf16x8*)(ebase + 32 * kt);                        \
        const f32x4 z = {0.f, 0.f, 0.f, 0.f};                                  \
        f32x4 a0 = z, a1 = z, a2 = z, a3 = z;                                  \
        f32x4 h0 = z, h1 = z, h2 = z, h3 = z;                                  \
        _Pragma("unroll")                                                      \
        for (int kt = 0; kt < 4; ++kt) {                                       \
            a0 = __builtin_amdgcn_mfma_f32_16x16x32_bf16(af[kt], bfr[kt][0], a0, 0, 0, 0); \
            a1 = __builtin_amdgcn_mfma_f32_16x16x32_bf16(af[kt], bfr[kt][1], a1, 0, 0, 0); \
            a2 = __builtin_amdgcn_mfma_f32_16x16x32_bf16(af[kt], bfr[kt][2], a2, 0, 0, 0); \
            a3 = __builtin_amdgcn_mfma_f32_16x16x32_bf16(af[kt], bfr[kt][3], a3, 0, 0, 0); \
        }                                                                      \
        _Pragma("unroll")                                                      \
        for (int kt = 4; kt < 8; ++kt) {                                       \
            h0 = __builtin_amdgcn_mfma_f32_16x16x32_bf16(af[kt], bfr[kt][0], h0, 0, 0, 0); \
            h1 = __builtin_amdgcn_mfma_f32_16x16x32_bf16(af[kt], bfr[kt][1], h1, 0, 0, 0); \
            h2 = __builtin_amdgcn_mfma_f32_16x16x32_bf16(af[kt], bfr[kt][2], h2, 0, 0, 0); \
            h3 = __builtin_amdgcn_mfma_f32_16x16x32_bf16(af[kt], bfr[kt][3], h3, 0, 0, 0); \
        }                                                                      \
        const float s0 = a0[0] + h0[0];                                        \
        const float s1 = a1[0] + h1[0];                                        \
        const float s2 = a2[0] + h2[0];                                        \
        const float s3 = a3[0] + h3[0];                                        \
        /* lane's u = tid = 64w + 16*g4 + c16  ->  pick n-tile g4 */           \
        const float sv = (g4 == 0) ? s0 : (g4 == 1) ? s1 : (g4 == 2) ? s2 : s3;\
        float ern = sv * __builtin_exp2f((PVC) * LOG2E);                       \
        if (((TT) & 7) == 0) {  /* deferred rescale, uniform branch */         \
            float m = wave_max64(ern);                                         \
            if (lane == 0) wred[w] = m;                                        \
            wg_barrier();                                                      \
            float g = fmaxf(fmaxf(wred[0], wred[1]), fmaxf(wred[2], wred[3])); \
            M += LN2 * __builtin_log2f(g);                                     \
            ern *= __builtin_amdgcn_rcpf(g);                                   \
        }                                                                      \
        er = ern;                                                              \
        ea_lds[(WP)][tid] = (__bf16)er;                                        \
        wg_barrier();                                                          \
    }

    // ---- main recursion: t = 1 .. L-1, unrolled x4 with depth-4 prefetch ----
    int t = 1;
    for (; t + 3 < L; t += 4) {
        {
            const float pvc = pv0;
            int tn = t + 4; if (tn > Tc - 1) tn = Tc - 1;
            pv0 = potb[(size_t)tn * Uc + tid];
            STEPBODY(t, pvc, (t + 1) & 1, t & 1);
        }
        {
            const float pvc = pv1;
            int tn = t + 5; if (tn > Tc - 1) tn = Tc - 1;
            pv1 = potb[(size_t)tn * Uc + tid];
            STEPBODY(t + 1, pvc, t & 1, (t + 1) & 1);
        }
        {
            const float pvc = pv2;
            int tn = t + 6; if (tn > Tc - 1) tn = Tc - 1;
            pv2 = potb[(size_t)tn * Uc + tid];
            STEPBODY(t + 2, pvc, (t + 1) & 1, t & 1);
        }
        {
            const float pvc = pv3;
            int tn = t + 7; if (tn > Tc - 1) tn = Tc - 1;
            pv3 = potb[(size_t)tn * Uc + tid];
            STEPBODY(t + 3, pvc, t & 1, (t + 1) & 1);
        }
    }
    for (; t < L; ++t) {   // tail (< 4 steps): direct loads, small stall ok
        const float pvc = potb[(size_t)t * Uc + tid];
        STEPBODY(t, pvc, (t + 1) & 1, t & 1);
    }

    // ---- epilogue: log_norm = M + log(sum_u ea[u]);  ll = U + B - logZ ----
    {
        float ssum = wave_sum64(er);
        if (lane == 0) wred[w] = ssum;
        __syncthreads();
        if (tid == 0) {
            const float S  = wred[0] + wred[1] + wred[2] + wred[3];
            const float uS = redU[0] + redU[1] + redU[2] + redU[3];
            const float bS = redB[0] + redB[1] + redB[2] + redB[3];
            const float logZ = M + LN2 * __builtin_log2f(S);
            ws[b] = uS + bS - logZ;
            __threadfence();
            // d_ws is re-poisoned to 0xAA before every launch (harness
            // contract), so the counter at ws[64] starts at 0xAAAAAAAA.
            unsigned old = atomicAdd((unsigned*)(ws + Bc), 1u);
            if (old == 0xAAAAAAAAu + (unsigned)(Bc - 1)) {
                __threadfence();
                float S2 = 0.f;
                #pragma unroll
                for (int i = 0; i < Bc; ++i) S2 += ws[i];
                out[0] = -S2 * (1.0f / (float)Bc);
            }
        }
    }
    #undef STEPBODY
}

extern "C" void kernel_launch(void* const* d_in, const int* in_sizes, int n_in,
                              void* d_out, int out_size, void* d_ws, size_t ws_size,
                              hipStream_t stream) {
    const float* pot   = (const float*)d_in[0];
    const int*   tags  = (const int*)d_in[1];
    const int*   slen  = (const int*)d_in[2];
    const float* trans = (const float*)d_in[3];
    float* wsf = (float*)d_ws;
    float* out = (float*)d_out;

    crf_fwd<<<Bc, 256, 0, stream>>>(pot, tags, slen, trans, wsf, out);
}

// Round 4
// 290.339 us; speedup vs baseline: 1.1456x; 1.1456x over previous
//
#include <hip/hip_runtime.h>

// CRF negative mean log-likelihood, B=64, T=512, U=256.
//
// Round 4: back to 8-wave skeleton (round-1, measured 228us vs round-3 277us)
// with the serial per-step tail attacked:
//  - deferred-apply rescale: divide by an 8-step-stale max passed via LDS
//    (mx[2][8]) -> NO second barrier, max-shfl chain off critical path.
//  - constant per-step normalizer folded into exp2 (CC2 = 5 nats in log2),
//    accounted exactly as (L-1)*c at the end; keeps values in fp range
//    despite stale feedback.
//  - exp2(pot) independent of MFMA result -> hidden under MFMA phase.
//  - clamp-free main loop; rescale check only in unroll body 4; tail reuses
//    prefetch registers.

#define Bc 64
#define Tc 512
#define Uc 256
#define LOG2E 1.4426950408889634f
#define LN2   0.6931471805599453f
#define CC2   7.2134752f   // per-step normalizer in log2 domain (= 5.0 nats)

typedef __bf16 bf16x8 __attribute__((ext_vector_type(8)));
typedef float  f32x4  __attribute__((ext_vector_type(4)));

// Raw barrier: does NOT drain vmcnt (pot prefetches stay in flight).
// lgkmcnt(0) makes our ds ops visible first.
__device__ __forceinline__ void wg_barrier() {
    asm volatile("s_waitcnt lgkmcnt(0)" ::: "memory");
    __builtin_amdgcn_s_barrier();
    asm volatile("" ::: "memory");
}

__global__ __launch_bounds__(512)
void crf_fwd(const float* __restrict__ pot, const int* __restrict__ tags,
             const int* __restrict__ seqlen, const float* __restrict__ trans,
             float* __restrict__ ws, float* __restrict__ out)
{
    const int b    = blockIdx.x;
    const int tid  = threadIdx.x;          // 0..511
    const int lane = tid & 63;
    const int w    = tid >> 6;             // wave 0..7
    const int g4   = lane >> 4;            // k-group 0..3
    const int c16  = lane & 15;            // fragment column
    const int L    = seqlen[b];

    __shared__ __align__(16) __bf16 ea_lds[2][Uc];
    __shared__ __align__(16) float mx[2][8];   // double-buffered wave maxes
    __shared__ float wred[8];
    __shared__ float redU[8], redB[8];

    const float* potb = pot  + (size_t)b * Tc * Uc;
    const int*   tagb = tags + b * Tc;

    // ---- B fragments: E = exp(trans), bf16, resident in registers ----
    // wave w owns n-tiles {2w, 2w+1} (u in [32w, 32w+32)).
    // elem e of lane l = E[v = 32kt + 8g4 + e][u = 32w + 16nt + c16].
    // Same (lane,e)->k placement as the A fragments (k-permutation cancels;
    // validated absmax 0.0 rounds 1/3).
    bf16x8 bfr[8][2];
    #pragma unroll
    for (int kt = 0; kt < 8; ++kt) {
        #pragma unroll
        for (int nt = 0; nt < 2; ++nt) {
            const int u = 32 * w + 16 * nt + c16;
            bf16x8 bb;
            #pragma unroll
            for (int e = 0; e < 8; ++e) {
                const int v = 32 * kt + 8 * g4 + e;
                bb[e] = (__bf16)__builtin_exp2f(trans[v * Uc + u] * LOG2E);
            }
            bfr[kt][nt] = bb;
        }
    }

    // ---- prologue: unary + binary scores, block-parallel over t ----
    {
        const int t  = tid;                // 0..511
        const int tg = tagb[t];
        float up = 0.f, bp = 0.f;
        if (t < L)           up = potb[(size_t)t * Uc + tg];
        if (t >= 1 && t < L) bp = trans[tagb[t - 1] * Uc + tg];
        #pragma unroll
        for (int m = 1; m < 64; m <<= 1) {
            up += __shfl_xor(up, m);
            bp += __shfl_xor(bp, m);
        }
        if (lane == 0) { redU[w] = up; redB[w] = bp; }
    }
    __syncthreads();

    const int um = 32 * w + (lane & 31);   // owned u (lanes>=32 duplicate)

    // pot prefetch registers, rows 1..4
    float pv0 = potb[(size_t)1 * Uc + um];
    float pv1 = potb[(size_t)2 * Uc + um];
    float pv2 = potb[(size_t)3 * Uc + um];
    float pv3 = potb[(size_t)4 * Uc + um];

    // ---- init (t = 0): er = exp(pot0)*r, M = -ln(r), r = rcp(max) ----
    float er = __builtin_exp2f(potb[um] * LOG2E);
    float M;
    {
        float m = er;
        m = fmaxf(m, __shfl_xor(m, 1));
        m = fmaxf(m, __shfl_xor(m, 2));
        m = fmaxf(m, __shfl_xor(m, 4));
        m = fmaxf(m, __shfl_xor(m, 8));
        m = fmaxf(m, __shfl_xor(m, 16));
        if (lane == 0) wred[w] = m;
        __syncthreads();
        float g = fmaxf(fmaxf(fmaxf(wred[0], wred[1]), fmaxf(wred[2], wred[3])),
                        fmaxf(fmaxf(wred[4], wred[5]), fmaxf(wred[6], wred[7])));
        const float r = __builtin_amdgcn_rcpf(g);
        M  = -LN2 * __builtin_log2f(r);    // exact log of applied scale
        er = er * r;
        if (lane < 32) ea_lds[0][um] = (__bf16)er;
        if (lane == 0) mx[1][w] = m * r;   // post-scale wave max, slot 1
        __syncthreads();
    }

    // One step. Reads ea_lds[RP], writes ea_lds[WP]. CHK: include deferred
    // rescale path (fires when TT%8==0; reads maxes written 8 steps ago).
    #define STEPX(TT, PVC, RP, WP, CHK)                                        \
    {                                                                          \
        bf16x8 af[8];                                                          \
        const __bf16* ebase = &ea_lds[(RP)][8 * g4];                           \
        _Pragma("unroll")                                                      \
        for (int kt = 0; kt < 8; ++kt)                                         \
            af[kt] = *(const bf16x8*)(ebase + 32 * kt);                        \
        float pef = __builtin_exp2f((PVC) * LOG2E - CC2);                      \
        float dM = 0.0f;                                                       \
        const bool dor = (CHK) && (((TT) & 7) == 0);                           \
        if (dor) {                                                             \
            const int sl = ((TT) >> 3) & 1;                                    \
            f32x4 m0 = *(const f32x4*)&mx[sl][0];                              \
            f32x4 m1 = *(const f32x4*)&mx[sl][4];                              \
            float g = fmaxf(fmaxf(fmaxf(m0[0], m0[1]), fmaxf(m0[2], m0[3])),   \
                            fmaxf(fmaxf(m1[0], m1[1]), fmaxf(m1[2], m1[3])));  \
            const float r = __builtin_amdgcn_rcpf(g);                          \
            dM  = -LN2 * __builtin_log2f(r);                                   \
            pef *= r;                                                          \
        }                                                                      \
        const f32x4 z = {0.f, 0.f, 0.f, 0.f};                                  \
        f32x4 c0l = z, c0h = z, c1l = z, c1h = z;                              \
        _Pragma("unroll")                                                      \
        for (int kt = 0; kt < 4; ++kt) {                                       \
            c0l = __builtin_amdgcn_mfma_f32_16x16x32_bf16(af[kt], bfr[kt][0], c0l, 0, 0, 0); \
            c1l = __builtin_amdgcn_mfma_f32_16x16x32_bf16(af[kt], bfr[kt][1], c1l, 0, 0, 0); \
        }                                                                      \
        _Pragma("unroll")                                                      \
        for (int kt = 4; kt < 8; ++kt) {                                       \
            c0h = __builtin_amdgcn_mfma_f32_16x16x32_bf16(af[kt], bfr[kt][0], c0h, 0, 0, 0); \
            c1h = __builtin_amdgcn_mfma_f32_16x16x32_bf16(af[kt], bfr[kt][1], c1h, 0, 0, 0); \
        }                                                                      \
        const float s0 = c0l[0] + c0h[0];                                      \
        const float s1 = c1l[0] + c1h[0];                                      \
        const float sv = (lane & 16) ? s1 : s0;                                \
        er = sv * pef;                                                         \
        if (lane < 32) ea_lds[(WP)][um] = (__bf16)er;                          \
        if (dor) {                                                             \
            M += dM;                                                           \
            float m = er;                                                      \
            m = fmaxf(m, __shfl_xor(m, 1));                                    \
            m = fmaxf(m, __shfl_xor(m, 2));                                    \
            m = fmaxf(m, __shfl_xor(m, 4));                                    \
            m = fmaxf(m, __shfl_xor(m, 8));                                    \
            m = fmaxf(m, __shfl_xor(m, 16));                                   \
            if (lane == 0) mx[(((TT) >> 3) & 1) ^ 1][w] = m;                   \
        }                                                                      \
        wg_barrier();                                                          \
    }

    // ---- main recursion: t = 1 .. , x4 unroll, clamp-free prefetch ----
    // t stays ≡ 1 (mod 4): bodies 1-3 can never hit TT%8==0 -> CHK=0.
    int t = 1;
    for (; t + 3 < L && t + 7 < Tc; t += 4) {
        {
            const float pvc = pv0;
            pv0 = potb[(size_t)(t + 4) * Uc + um];
            STEPX(t, pvc, (t + 1) & 1, t & 1, 0);
        }
        {
            const float pvc = pv1;
            pv1 = potb[(size_t)(t + 5) * Uc + um];
            STEPX(t + 1, pvc, t & 1, (t + 1) & 1, 0);
        }
        {
            const float pvc = pv2;
            pv2 = potb[(size_t)(t + 6) * Uc + um];
            STEPX(t + 2, pvc, (t + 1) & 1, t & 1, 0);
        }
        {
            const float pvc = pv3;
            pv3 = potb[(size_t)(t + 7) * Uc + um];
            STEPX(t + 3, pvc, t & 1, (t + 1) & 1, 1);
        }
    }
    // ---- tail: first 4 steps reuse still-valid prefetches ----
    if (t < L) { STEPX(t, pv0, (t + 1) & 1, t & 1, 1); ++t; }
    if (t < L) { STEPX(t, pv1, (t + 1) & 1, t & 1, 1); ++t; }
    if (t < L) { STEPX(t, pv2, (t + 1) & 1, t & 1, 1); ++t; }
    if (t < L) { STEPX(t, pv3, (t + 1) & 1, t & 1, 1); ++t; }
    for (; t < L; ++t) {
        const float pvc = potb[(size_t)t * Uc + um];
        STEPX(t, pvc, (t + 1) & 1, t & 1, 1);
    }

    // ---- epilogue: logZ = M + (L-1)*c + ln(sum er);  ll = U + B - logZ ----
    {
        float ssum = er;
        ssum += __shfl_xor(ssum, 1);
        ssum += __shfl_xor(ssum, 2);
        ssum += __shfl_xor(ssum, 4);
        ssum += __shfl_xor(ssum, 8);
        ssum += __shfl_xor(ssum, 16);      // sum over 32 unique lanes
        if (lane == 0) wred[w] = ssum;
        __syncthreads();
        if (tid == 0) {
            float S = 0.f, uS = 0.f, bS = 0.f;
            #pragma unroll
            for (int i = 0; i < 8; ++i) { S += wred[i]; uS += redU[i]; bS += redB[i]; }
            const float cstep = CC2 * LN2;           // = 5.0 nats per step
            const float logZ = M + (float)(L - 1) * cstep
                             + LN2 * __builtin_log2f(S);
            ws[b] = uS + bS - logZ;
            __threadfence();
            // d_ws is re-poisoned to 0xAA before every launch (harness
            // contract) -> counter at ws[64] starts at 0xAAAAAAAA.
            unsigned old = atomicAdd((unsigned*)(ws + Bc), 1u);
            if (old == 0xAAAAAAAAu + (unsigned)(Bc - 1)) {
                __threadfence();
                float S2 = 0.f;
                #pragma unroll
                for (int i = 0; i < Bc; ++i) S2 += ws[i];
                out[0] = -S2 * (1.0f / (float)Bc);
            }
        }
    }
    #undef STEPX
}

extern "C" void kernel_launch(void* const* d_in, const int* in_sizes, int n_in,
                              void* d_out, int out_size, void* d_ws, size_t ws_size,
                              hipStream_t stream) {
    const float* pot   = (const float*)d_in[0];
    const int*   tags  = (const int*)d_in[1];
    const int*   slen  = (const int*)d_in[2];
    const float* trans = (const float*)d_in[3];
    float* wsf = (float*)d_ws;
    float* out = (float*)d_out;

    crf_fwd<<<Bc, 512, 0, stream>>>(pot, tags, slen, trans, wsf, out);
}